// Round 8
// baseline (599.877 us; speedup 1.0000x reference)
//
// R8: register-streaming GEMMs — no LDS, no K-loop barriers. Each lane loads
// its MFMA fragments directly (global_load_dwordx4, 2-deep SW pipeline);
// L1 dedups the 2x wave overlap. ctx keeps split-K x4 + XCD swizzle + atomics.
#include <hip/hip_runtime.h>

#define NQ 4096
#define NK 8192
#define DIM 1024

typedef __attribute__((ext_vector_type(8))) short short8;
typedef __attribute__((ext_vector_type(4))) float floatx4;

__device__ __forceinline__ unsigned short f32_bf16(float f) {
    unsigned int u = __float_as_uint(f);
    u += 0x7fff + ((u >> 16) & 1);
    return (unsigned short)(u >> 16);
}

// ---------------------------------------------------------------------------
// Q prep + zero(out) + zero(lsum)
// ---------------------------------------------------------------------------
__global__ void prep_q_zero(const float* __restrict__ Q,
                            unsigned short* __restrict__ Qb,
                            float* __restrict__ inv_qn,
                            float* __restrict__ lsum,
                            float* __restrict__ out) {
    int wave = threadIdx.x >> 6;
    int lane = threadIdx.x & 63;
    int row  = blockIdx.x * 4 + wave;
    const float* r = Q + (size_t)row * DIM;
    float s = 0.f;
#pragma unroll
    for (int c = 0; c < 4; ++c) {
        float4 f = *(const float4*)(r + c * 256 + lane * 4);
        s += f.x * f.x + f.y * f.y + f.z * f.z + f.w * f.w;
        ushort4 b;
        b.x = f32_bf16(f.x); b.y = f32_bf16(f.y);
        b.z = f32_bf16(f.z); b.w = f32_bf16(f.w);
        *(ushort4*)(Qb + (size_t)row * DIM + c * 256 + lane * 4) = b;
    }
#pragma unroll
    for (int off = 32; off > 0; off >>= 1) s += __shfl_xor(s, off);
    if (lane == 0) inv_qn[row] = 1.0f / sqrtf(s);

    float4 z = make_float4(0.f, 0.f, 0.f, 0.f);
#pragma unroll
    for (int c = 0; c < 4; ++c)
        *(float4*)(out + (size_t)blockIdx.x * 4096 + c * 1024 + threadIdx.x * 4) = z;
    if (blockIdx.x < 4)
        *(float4*)(lsum + blockIdx.x * 1024 + threadIdx.x * 4) = z;
}

// ---------------------------------------------------------------------------
// K prep: bf16 convert + 1/norm
// ---------------------------------------------------------------------------
__global__ void prep_norm_cvt(const float* __restrict__ src,
                              unsigned short* __restrict__ dst,
                              float* __restrict__ inv_norm) {
    int wave = threadIdx.x >> 6;
    int lane = threadIdx.x & 63;
    int row  = blockIdx.x * 4 + wave;
    const float* r = src + (size_t)row * DIM;
    float s = 0.f;
#pragma unroll
    for (int c = 0; c < 4; ++c) {
        float4 f = *(const float4*)(r + c * 256 + lane * 4);
        s += f.x * f.x + f.y * f.y + f.z * f.z + f.w * f.w;
        ushort4 b;
        b.x = f32_bf16(f.x); b.y = f32_bf16(f.y);
        b.z = f32_bf16(f.z); b.w = f32_bf16(f.w);
        *(ushort4*)(dst + (size_t)row * DIM + c * 256 + lane * 4) = b;
    }
#pragma unroll
    for (int off = 32; off > 0; off >>= 1) s += __shfl_xor(s, off);
    if (lane == 0) inv_norm[row] = 1.0f / sqrtf(s);
}

// ---------------------------------------------------------------------------
// transpose + convert: Kt[d][kn] = bf16(K[kn][d])
// ---------------------------------------------------------------------------
__global__ void transpose_cvt(const float* __restrict__ K,
                              unsigned short* __restrict__ Kt) {
    __shared__ float t[64][65];
    int kn0 = blockIdx.x * 64, d0 = blockIdx.y * 64;
    int tid = threadIdx.x;
    int r  = tid >> 4;
    int c4 = (tid & 15) * 4;
#pragma unroll
    for (int s = 0; s < 4; ++s) {
        int kk = s * 16 + r;
        float4 f = *(const float4*)(K + (size_t)(kn0 + kk) * DIM + d0 + c4);
        t[kk][c4 + 0] = f.x; t[kk][c4 + 1] = f.y;
        t[kk][c4 + 2] = f.z; t[kk][c4 + 3] = f.w;
    }
    __syncthreads();
#pragma unroll
    for (int s = 0; s < 4; ++s) {
        int dd = s * 16 + r;
        ushort4 b;
        b.x = f32_bf16(t[c4 + 0][dd]);
        b.y = f32_bf16(t[c4 + 1][dd]);
        b.z = f32_bf16(t[c4 + 2][dd]);
        b.w = f32_bf16(t[c4 + 3][dd]);
        *(ushort4*)(Kt + (size_t)(d0 + dd) * NK + kn0 + c4) = b;
    }
}

// ---------------------------------------------------------------------------
// GEMM 1 (streaming, operand-swapped): no LDS, no barriers.
// pA[i]: q-row (q0+wm*64+i*16+l16), 16B chunk quad*8; pB[j]: key-row.
// 2-deep pipeline over 32 K-steps; epilogue = packed ushort4 P + rowsum.
// ---------------------------------------------------------------------------
__global__ void score_gemm(const unsigned short* __restrict__ Qb,
                           const unsigned short* __restrict__ Kb,
                           const float* __restrict__ inv_qn,
                           const float* __restrict__ inv_kn,
                           unsigned short* __restrict__ P,
                           float* __restrict__ lsum) {
    int q0 = blockIdx.y * 128;
    int n0 = blockIdx.x * 128;
    int tid = threadIdx.x;
    int wave = tid >> 6, lane = tid & 63;
    int wm = wave >> 1, wn = wave & 1;
    int quad = lane >> 4, l16 = lane & 15;

    const unsigned short* pA[4];
    const unsigned short* pB[4];
#pragma unroll
    for (int i = 0; i < 4; ++i) {
        pA[i] = Qb + (size_t)(q0 + wm * 64 + i * 16 + l16) * DIM + quad * 8;
        pB[i] = Kb + (size_t)(n0 + wn * 64 + i * 16 + l16) * DIM + quad * 8;
    }

    floatx4 acc[4][4];
#pragma unroll
    for (int i = 0; i < 4; ++i)
#pragma unroll
        for (int j = 0; j < 4; ++j) acc[i][j] = (floatx4)(0.0f);

    short8 a0[4], b0[4], a1[4], b1[4];

#define SLOAD(A_, B_, kk)                                     \
    {                                                         \
        _Pragma("unroll")                                     \
        for (int i = 0; i < 4; ++i) {                         \
            A_[i] = *(const short8*)(pA[i] + (kk) * 32);      \
            B_[i] = *(const short8*)(pB[i] + (kk) * 32);      \
        }                                                     \
    }
#define SMFMA(A_, B_)                                                          \
    {                                                                          \
        _Pragma("unroll")                                                      \
        for (int i = 0; i < 4; ++i)                                            \
            _Pragma("unroll")                                                  \
            for (int j = 0; j < 4; ++j)                                        \
                acc[i][j] = __builtin_amdgcn_mfma_f32_16x16x32_bf16(           \
                    B_[j], A_[i], acc[i][j], 0, 0, 0);                         \
    }

    SLOAD(a0, b0, 0);
    int kb = 0;
    for (; kb + 2 < DIM / 32; kb += 2) {
        SLOAD(a1, b1, kb + 1);
        SMFMA(a0, b0);
        SLOAD(a0, b0, kb + 2);
        SMFMA(a1, b1);
    }
    SLOAD(a1, b1, kb + 1);
    SMFMA(a0, b0);
    SMFMA(a1, b1);
#undef SLOAD
#undef SMFMA

#pragma unroll
    for (int i = 0; i < 4; ++i) {
        int qrow = q0 + wm * 64 + i * 16 + l16;
        float iqn = inv_qn[qrow];
        float rs = 0.f;
#pragma unroll
        for (int j = 0; j < 4; ++j) {
            int ncol = n0 + wn * 64 + j * 16 + quad * 4;
            float4 ik = *(const float4*)&inv_kn[ncol];
            float p0 = __expf(acc[i][j][0] * iqn * ik.x);
            float p1 = __expf(acc[i][j][1] * iqn * ik.y);
            float p2 = __expf(acc[i][j][2] * iqn * ik.z);
            float p3 = __expf(acc[i][j][3] * iqn * ik.w);
            ushort4 pb;
            pb.x = f32_bf16(p0); pb.y = f32_bf16(p1);
            pb.z = f32_bf16(p2); pb.w = f32_bf16(p3);
            *(ushort4*)&P[(size_t)qrow * NK + ncol] = pb;
            rs += p0 + p1 + p2 + p3;
        }
        rs += __shfl_xor(rs, 16);
        rs += __shfl_xor(rs, 32);
        if (quad == 0) atomicAdd(&lsum[qrow], rs);
    }
}

// ---------------------------------------------------------------------------
// GEMM 2 (streaming, split-K x4 + XCD swizzle): no LDS, no barriers.
// grid 1024 1D; group's 8 d-blocks share id%8 => same XCD => P-strip L2 reuse.
// ---------------------------------------------------------------------------
__global__ void ctx_gemm(const unsigned short* __restrict__ P,
                         const unsigned short* __restrict__ Kt,
                         const float* __restrict__ lsum,
                         float* __restrict__ out) {
    int id = blockIdx.x;
    int r8 = id & 7;
    int t  = id >> 3;
    int x  = t & 7;
    int g  = ((t >> 3) << 3) | r8;   // 0..127
    int y  = g & 31;
    int z  = g >> 5;                 // 0..3
    int q0 = y * 128;
    int d0 = x * 128;
    int kbase = z * (NK / 4);

    int tid = threadIdx.x;
    int wave = tid >> 6, lane = tid & 63;
    int wm = wave >> 1, wn = wave & 1;
    int quad = lane >> 4, l16 = lane & 15;

    const unsigned short* pA[4];
    const unsigned short* pB[4];
#pragma unroll
    for (int i = 0; i < 4; ++i) {
        pA[i] = P  + (size_t)(q0 + wm * 64 + i * 16 + l16) * NK + kbase + quad * 8;
        pB[i] = Kt + (size_t)(d0 + wn * 64 + i * 16 + l16) * NK + kbase + quad * 8;
    }

    floatx4 acc[4][4];
#pragma unroll
    for (int i = 0; i < 4; ++i)
#pragma unroll
        for (int j = 0; j < 4; ++j) acc[i][j] = (floatx4)(0.0f);

    short8 a0[4], b0[4], a1[4], b1[4];

#define CLOAD(A_, B_, kk)                                     \
    {                                                         \
        _Pragma("unroll")                                     \
        for (int i = 0; i < 4; ++i) {                         \
            A_[i] = *(const short8*)(pA[i] + (kk) * 32);      \
            B_[i] = *(const short8*)(pB[i] + (kk) * 32);      \
        }                                                     \
    }
#define CMFMA(A_, B_)                                                          \
    {                                                                          \
        _Pragma("unroll")                                                      \
        for (int i = 0; i < 4; ++i)                                            \
            _Pragma("unroll")                                                  \
            for (int j = 0; j < 4; ++j)                                        \
                acc[i][j] = __builtin_amdgcn_mfma_f32_16x16x32_bf16(           \
                    A_[i], B_[j], acc[i][j], 0, 0, 0);                         \
    }

    CLOAD(a0, b0, 0);
    int kb = 0;
    for (; kb + 2 < (NK / 4) / 32; kb += 2) {
        CLOAD(a1, b1, kb + 1);
        CMFMA(a0, b0);
        CLOAD(a0, b0, kb + 2);
        CMFMA(a1, b1);
    }
    CLOAD(a1, b1, kb + 1);
    CMFMA(a0, b0);
    CMFMA(a1, b1);
#undef CLOAD
#undef CMFMA

#pragma unroll
    for (int i = 0; i < 4; ++i) {
        float invl[4];
#pragma unroll
        for (int r = 0; r < 4; ++r)
            invl[r] = 1.0f / lsum[q0 + wm * 64 + i * 16 + quad * 4 + r];
#pragma unroll
        for (int j = 0; j < 4; ++j) {
#pragma unroll
            for (int r = 0; r < 4; ++r) {
                int qrow = q0 + wm * 64 + i * 16 + quad * 4 + r;
                int dcol = d0 + wn * 64 + j * 16 + l16;
                atomicAdd(&out[(size_t)qrow * DIM + dcol], acc[i][j][r] * invl[r]);
            }
        }
    }
}

// ---------------------------------------------------------------------------
// Path D fallback (ws too small) — correct but slow.
// ---------------------------------------------------------------------------
__global__ void fused_fallback(const float* __restrict__ Q,
                               const float* __restrict__ K,
                               float* __restrict__ out) {
    int wave = threadIdx.x >> 6, lane = threadIdx.x & 63;
    int q0 = blockIdx.x * 16 + wave * 4;
    float qv[4][16], acc[4][16], iqn[4], ls[4];
#pragma unroll
    for (int r = 0; r < 4; ++r) {
        float s = 0.f;
#pragma unroll
        for (int c = 0; c < 4; ++c) {
            float4 f = *(const float4*)(Q + (size_t)(q0 + r) * DIM + c * 256 + lane * 4);
            qv[r][c * 4 + 0] = f.x; qv[r][c * 4 + 1] = f.y;
            qv[r][c * 4 + 2] = f.z; qv[r][c * 4 + 3] = f.w;
            s += f.x * f.x + f.y * f.y + f.z * f.z + f.w * f.w;
        }
#pragma unroll
        for (int off = 32; off > 0; off >>= 1) s += __shfl_xor(s, off);
        iqn[r] = 1.0f / sqrtf(s);
        ls[r] = 0.f;
#pragma unroll
        for (int t = 0; t < 16; ++t) acc[r][t] = 0.f;
    }
    for (int k = 0; k < NK; ++k) {
        const float* kr = K + (size_t)k * DIM;
        float kv[16], ss = 0.f;
#pragma unroll
        for (int c = 0; c < 4; ++c) {
            float4 f = *(const float4*)(kr + c * 256 + lane * 4);
            kv[c * 4 + 0] = f.x; kv[c * 4 + 1] = f.y;
            kv[c * 4 + 2] = f.z; kv[c * 4 + 3] = f.w;
            ss += f.x * f.x + f.y * f.y + f.z * f.z + f.w * f.w;
        }
        float d0 = 0.f, d1 = 0.f, d2 = 0.f, d3 = 0.f;
#pragma unroll
        for (int t = 0; t < 16; ++t) {
            d0 += qv[0][t] * kv[t]; d1 += qv[1][t] * kv[t];
            d2 += qv[2][t] * kv[t]; d3 += qv[3][t] * kv[t];
        }
#pragma unroll
        for (int off = 32; off > 0; off >>= 1) {
            ss += __shfl_xor(ss, off);
            d0 += __shfl_xor(d0, off); d1 += __shfl_xor(d1, off);
            d2 += __shfl_xor(d2, off); d3 += __shfl_xor(d3, off);
        }
        float ikn = 1.0f / sqrtf(ss);
        float p0 = __expf(d0 * iqn[0] * ikn), p1 = __expf(d1 * iqn[1] * ikn);
        float p2 = __expf(d2 * iqn[2] * ikn), p3 = __expf(d3 * iqn[3] * ikn);
        ls[0] += p0; ls[1] += p1; ls[2] += p2; ls[3] += p3;
#pragma unroll
        for (int t = 0; t < 16; ++t) {
            acc[0][t] += p0 * kv[t]; acc[1][t] += p1 * kv[t];
            acc[2][t] += p2 * kv[t]; acc[3][t] += p3 * kv[t];
        }
    }
#pragma unroll
    for (int r = 0; r < 4; ++r) {
        float inv = 1.0f / ls[r];
#pragma unroll
        for (int c = 0; c < 4; ++c) {
            float4 o;
            o.x = acc[r][c * 4 + 0] * inv; o.y = acc[r][c * 4 + 1] * inv;
            o.z = acc[r][c * 4 + 2] * inv; o.w = acc[r][c * 4 + 3] * inv;
            *(float4*)(out + (size_t)(q0 + r) * DIM + c * 256 + lane * 4) = o;
        }
    }
}

// ---------------------------------------------------------------------------
// launch — ws layout unchanged: Kt [0,16M) overlaps Qb/Kb (dead after score);
// P [24M,88M); inv_qn/inv_kn/lsum at 88M.
// ---------------------------------------------------------------------------
extern "C" void kernel_launch(void* const* d_in, const int* in_sizes, int n_in,
                              void* d_out, int out_size, void* d_ws, size_t ws_size,
                              hipStream_t stream) {
    const float* Q = (const float*)d_in[0];
    const float* K = (const float*)d_in[1];
    float* out = (float*)d_out;
    char* ws = (char*)d_ws;

    const size_t REQ_A = ((size_t)88u << 20) + 65536;
    if (ws_size >= REQ_A) {
        unsigned short* Kt = (unsigned short*)(ws);
        unsigned short* Qb = (unsigned short*)(ws);
        unsigned short* Kb = (unsigned short*)(ws + (size_t)(8u << 20));
        unsigned short* P  = (unsigned short*)(ws + (size_t)(24u << 20));
        float* inv_qn = (float*)(ws + (size_t)(88u << 20));
        float* inv_kn = (float*)(ws + (size_t)(88u << 20) + 16384);
        float* lsum   = (float*)(ws + (size_t)(88u << 20) + 49152);

        prep_q_zero<<<NQ / 4, 256, 0, stream>>>(Q, Qb, inv_qn, lsum, out);
        prep_norm_cvt<<<NK / 4, 256, 0, stream>>>(K, Kb, inv_kn);
        score_gemm<<<dim3(NK / 128, NQ / 128), 256, 0, stream>>>(Qb, Kb, inv_qn, inv_kn, P, lsum);
        transpose_cvt<<<dim3(NK / 64, DIM / 64), 256, 0, stream>>>(K, Kt);
        ctx_gemm<<<1024, 256, 0, stream>>>(P, Kt, lsum, out);
    } else {
        fused_fallback<<<NQ / 16, 256, 0, stream>>>(Q, K, out);
    }
}

// Round 9
// 318.375 us; speedup vs baseline: 1.8842x; 1.8842x over previous
//
// R9: R7 base (R8 register-streaming regressed 2x -> reverted).
//  (a) score: XCD swizzle, q-tile pinned to XCD (Qb strip L2-resident).
//  (b) both GEMMs: BK=64 as dual unpadded 128x32 panels -> half the barrier
//      drains, 8 global_load_lds outstanding per wave per drain.
#include <hip/hip_runtime.h>

#define NQ 4096
#define NK 8192
#define DIM 1024

typedef __attribute__((ext_vector_type(8))) short short8;
typedef __attribute__((ext_vector_type(4))) float floatx4;
typedef unsigned int u32;
typedef __attribute__((address_space(3))) u32 lds_u32;
typedef __attribute__((address_space(1))) const u32 glb_u32;

__device__ __forceinline__ void gload_lds16(const void* g, void* l) {
    __builtin_amdgcn_global_load_lds((glb_u32*)g, (lds_u32*)l, 16, 0, 0);
}

__device__ __forceinline__ unsigned short f32_bf16(float f) {
    unsigned int u = __float_as_uint(f);
    u += 0x7fff + ((u >> 16) & 1);
    return (unsigned short)(u >> 16);
}

// ---------------------------------------------------------------------------
// Q prep + zero(out) + zero(lsum)
// ---------------------------------------------------------------------------
__global__ void prep_q_zero(const float* __restrict__ Q,
                            unsigned short* __restrict__ Qb,
                            float* __restrict__ inv_qn,
                            float* __restrict__ lsum,
                            float* __restrict__ out) {
    int wave = threadIdx.x >> 6;
    int lane = threadIdx.x & 63;
    int row  = blockIdx.x * 4 + wave;
    const float* r = Q + (size_t)row * DIM;
    float s = 0.f;
#pragma unroll
    for (int c = 0; c < 4; ++c) {
        float4 f = *(const float4*)(r + c * 256 + lane * 4);
        s += f.x * f.x + f.y * f.y + f.z * f.z + f.w * f.w;
        ushort4 b;
        b.x = f32_bf16(f.x); b.y = f32_bf16(f.y);
        b.z = f32_bf16(f.z); b.w = f32_bf16(f.w);
        *(ushort4*)(Qb + (size_t)row * DIM + c * 256 + lane * 4) = b;
    }
#pragma unroll
    for (int off = 32; off > 0; off >>= 1) s += __shfl_xor(s, off);
    if (lane == 0) inv_qn[row] = 1.0f / sqrtf(s);

    float4 z = make_float4(0.f, 0.f, 0.f, 0.f);
#pragma unroll
    for (int c = 0; c < 4; ++c)
        *(float4*)(out + (size_t)blockIdx.x * 4096 + c * 1024 + threadIdx.x * 4) = z;
    if (blockIdx.x < 4)
        *(float4*)(lsum + blockIdx.x * 1024 + threadIdx.x * 4) = z;
}

// ---------------------------------------------------------------------------
// K prep: bf16 convert + 1/norm
// ---------------------------------------------------------------------------
__global__ void prep_norm_cvt(const float* __restrict__ src,
                              unsigned short* __restrict__ dst,
                              float* __restrict__ inv_norm) {
    int wave = threadIdx.x >> 6;
    int lane = threadIdx.x & 63;
    int row  = blockIdx.x * 4 + wave;
    const float* r = src + (size_t)row * DIM;
    float s = 0.f;
#pragma unroll
    for (int c = 0; c < 4; ++c) {
        float4 f = *(const float4*)(r + c * 256 + lane * 4);
        s += f.x * f.x + f.y * f.y + f.z * f.z + f.w * f.w;
        ushort4 b;
        b.x = f32_bf16(f.x); b.y = f32_bf16(f.y);
        b.z = f32_bf16(f.z); b.w = f32_bf16(f.w);
        *(ushort4*)(dst + (size_t)row * DIM + c * 256 + lane * 4) = b;
    }
#pragma unroll
    for (int off = 32; off > 0; off >>= 1) s += __shfl_xor(s, off);
    if (lane == 0) inv_norm[row] = 1.0f / sqrtf(s);
}

// ---------------------------------------------------------------------------
// transpose + convert: Kt[d][kn] = bf16(K[kn][d])
// ---------------------------------------------------------------------------
__global__ void transpose_cvt(const float* __restrict__ K,
                              unsigned short* __restrict__ Kt) {
    __shared__ float t[64][65];
    int kn0 = blockIdx.x * 64, d0 = blockIdx.y * 64;
    int tid = threadIdx.x;
    int r  = tid >> 4;
    int c4 = (tid & 15) * 4;
#pragma unroll
    for (int s = 0; s < 4; ++s) {
        int kk = s * 16 + r;
        float4 f = *(const float4*)(K + (size_t)(kn0 + kk) * DIM + d0 + c4);
        t[kk][c4 + 0] = f.x; t[kk][c4 + 1] = f.y;
        t[kk][c4 + 2] = f.z; t[kk][c4 + 3] = f.w;
    }
    __syncthreads();
#pragma unroll
    for (int s = 0; s < 4; ++s) {
        int dd = s * 16 + r;
        ushort4 b;
        b.x = f32_bf16(t[c4 + 0][dd]);
        b.y = f32_bf16(t[c4 + 1][dd]);
        b.z = f32_bf16(t[c4 + 2][dd]);
        b.w = f32_bf16(t[c4 + 3][dd]);
        *(ushort4*)(Kt + (size_t)(d0 + dd) * NK + kn0 + c4) = b;
    }
}

// ---------------------------------------------------------------------------
// GEMM 1 (operand-swapped, BK=64 dual panels, XCD-swizzled grid 2048 1D):
// id%8 = XCD; q-tile = qhi*8 + (id&7) => all 64 n-blocks of a q-tile share one
// XCD (Qb strip L2-resident); n inner.
// ---------------------------------------------------------------------------
__global__ void score_gemm(const unsigned short* __restrict__ Qb,
                           const unsigned short* __restrict__ Kb,
                           const float* __restrict__ inv_qn,
                           const float* __restrict__ inv_kn,
                           unsigned short* __restrict__ P,
                           float* __restrict__ lsum) {
    __shared__ __align__(16) unsigned short As0[128 * 32];
    __shared__ __align__(16) unsigned short As1[128 * 32];
    __shared__ __align__(16) unsigned short Bs0[128 * 32];
    __shared__ __align__(16) unsigned short Bs1[128 * 32];

    int id  = blockIdx.x;
    int r8  = id & 7;
    int t   = id >> 3;
    int n   = t & 63;
    int qhi = t >> 6;              // 0..3
    int q0  = (qhi * 8 + r8) * 128;
    int n0  = n * 128;

    int tid = threadIdx.x;
    int wave = tid >> 6, lane = tid & 63;
    int wm = wave >> 1, wn = wave & 1;
    int quad = lane >> 4, l16 = lane & 15;

    int srow   = wave * 32 + (lane >> 2);
    int schunk = (lane & 3) * 8;
    const unsigned short* gA = Qb + (size_t)(q0 + srow) * DIM + schunk;
    const unsigned short* gB = Kb + (size_t)(n0 + srow) * DIM + schunk;
    unsigned short* lA0 = As0 + wave * 32 * 32;
    unsigned short* lA1 = As1 + wave * 32 * 32;
    unsigned short* lB0 = Bs0 + wave * 32 * 32;
    unsigned short* lB1 = Bs1 + wave * 32 * 32;

    floatx4 acc[4][4];
#pragma unroll
    for (int i = 0; i < 4; ++i)
#pragma unroll
        for (int j = 0; j < 4; ++j) acc[i][j] = (floatx4)(0.0f);

    for (int kb = 0; kb < DIM / 64; ++kb) {
        int d0 = kb * 64;
        __syncthreads();
        gload_lds16(gA + d0, lA0);
        gload_lds16(gA + (size_t)16 * DIM + d0, lA0 + 16 * 32);
        gload_lds16(gA + d0 + 32, lA1);
        gload_lds16(gA + (size_t)16 * DIM + d0 + 32, lA1 + 16 * 32);
        gload_lds16(gB + d0, lB0);
        gload_lds16(gB + (size_t)16 * DIM + d0, lB0 + 16 * 32);
        gload_lds16(gB + d0 + 32, lB1);
        gload_lds16(gB + (size_t)16 * DIM + d0 + 32, lB1 + 16 * 32);
        __syncthreads();
        short8 a[4], b[4];
#pragma unroll
        for (int i = 0; i < 4; ++i)
            a[i] = *(const short8*)&As0[(wm * 64 + i * 16 + l16) * 32 + quad * 8];
#pragma unroll
        for (int j = 0; j < 4; ++j)
            b[j] = *(const short8*)&Bs0[(wn * 64 + j * 16 + l16) * 32 + quad * 8];
#pragma unroll
        for (int i = 0; i < 4; ++i)
#pragma unroll
            for (int j = 0; j < 4; ++j)
                acc[i][j] = __builtin_amdgcn_mfma_f32_16x16x32_bf16(b[j], a[i], acc[i][j], 0, 0, 0);
#pragma unroll
        for (int i = 0; i < 4; ++i)
            a[i] = *(const short8*)&As1[(wm * 64 + i * 16 + l16) * 32 + quad * 8];
#pragma unroll
        for (int j = 0; j < 4; ++j)
            b[j] = *(const short8*)&Bs1[(wn * 64 + j * 16 + l16) * 32 + quad * 8];
#pragma unroll
        for (int i = 0; i < 4; ++i)
#pragma unroll
            for (int j = 0; j < 4; ++j)
                acc[i][j] = __builtin_amdgcn_mfma_f32_16x16x32_bf16(b[j], a[i], acc[i][j], 0, 0, 0);
    }

#pragma unroll
    for (int i = 0; i < 4; ++i) {
        int qrow = q0 + wm * 64 + i * 16 + l16;
        float iqn = inv_qn[qrow];
        float rs = 0.f;
#pragma unroll
        for (int j = 0; j < 4; ++j) {
            int ncol = n0 + wn * 64 + j * 16 + quad * 4;
            float4 ik = *(const float4*)&inv_kn[ncol];
            float p0 = __expf(acc[i][j][0] * iqn * ik.x);
            float p1 = __expf(acc[i][j][1] * iqn * ik.y);
            float p2 = __expf(acc[i][j][2] * iqn * ik.z);
            float p3 = __expf(acc[i][j][3] * iqn * ik.w);
            ushort4 pb;
            pb.x = f32_bf16(p0); pb.y = f32_bf16(p1);
            pb.z = f32_bf16(p2); pb.w = f32_bf16(p3);
            *(ushort4*)&P[(size_t)qrow * NK + ncol] = pb;
            rs += p0 + p1 + p2 + p3;
        }
        rs += __shfl_xor(rs, 16);
        rs += __shfl_xor(rs, 32);
        if (quad == 0) atomicAdd(&lsum[qrow], rs);
    }
}

// ---------------------------------------------------------------------------
// GEMM 2: split-K x4 + XCD swizzle (R7), BK=64 dual panels. grid 1024 1D.
// ---------------------------------------------------------------------------
__global__ void ctx_gemm(const unsigned short* __restrict__ P,
                         const unsigned short* __restrict__ Kt,
                         const float* __restrict__ lsum,
                         float* __restrict__ out) {
    __shared__ __align__(16) unsigned short As0[128 * 32];
    __shared__ __align__(16) unsigned short As1[128 * 32];
    __shared__ __align__(16) unsigned short Bs0[128 * 32];
    __shared__ __align__(16) unsigned short Bs1[128 * 32];

    int id = blockIdx.x;
    int r8 = id & 7;
    int t  = id >> 3;
    int x  = t & 7;
    int g  = ((t >> 3) << 3) | r8;   // 0..127
    int y  = g & 31;
    int z  = g >> 5;                 // 0..3
    int q0 = y * 128;
    int d0 = x * 128;
    int kbase = z * (NK / 4);

    int tid = threadIdx.x;
    int wave = tid >> 6, lane = tid & 63;
    int wm = wave >> 1, wn = wave & 1;
    int quad = lane >> 4, l16 = lane & 15;

    int srow   = wave * 32 + (lane >> 2);
    int schunk = (lane & 3) * 8;
    const unsigned short* gA = P  + (size_t)(q0 + srow) * NK + kbase + schunk;
    const unsigned short* gB = Kt + (size_t)(d0 + srow) * NK + kbase + schunk;
    unsigned short* lA0 = As0 + wave * 32 * 32;
    unsigned short* lA1 = As1 + wave * 32 * 32;
    unsigned short* lB0 = Bs0 + wave * 32 * 32;
    unsigned short* lB1 = Bs1 + wave * 32 * 32;

    floatx4 acc[4][4];
#pragma unroll
    for (int i = 0; i < 4; ++i)
#pragma unroll
        for (int j = 0; j < 4; ++j) acc[i][j] = (floatx4)(0.0f);

    for (int kb = 0; kb < (NK / 4) / 64; ++kb) {
        int k0 = kb * 64;
        __syncthreads();
        gload_lds16(gA + k0, lA0);
        gload_lds16(gA + (size_t)16 * NK + k0, lA0 + 16 * 32);
        gload_lds16(gA + k0 + 32, lA1);
        gload_lds16(gA + (size_t)16 * NK + k0 + 32, lA1 + 16 * 32);
        gload_lds16(gB + k0, lB0);
        gload_lds16(gB + (size_t)16 * NK + k0, lB0 + 16 * 32);
        gload_lds16(gB + k0 + 32, lB1);
        gload_lds16(gB + (size_t)16 * NK + k0 + 32, lB1 + 16 * 32);
        __syncthreads();
        short8 a[4], b[4];
#pragma unroll
        for (int i = 0; i < 4; ++i)
            a[i] = *(const short8*)&As0[(wm * 64 + i * 16 + l16) * 32 + quad * 8];
#pragma unroll
        for (int j = 0; j < 4; ++j)
            b[j] = *(const short8*)&Bs0[(wn * 64 + j * 16 + l16) * 32 + quad * 8];
#pragma unroll
        for (int i = 0; i < 4; ++i)
#pragma unroll
            for (int j = 0; j < 4; ++j)
                acc[i][j] = __builtin_amdgcn_mfma_f32_16x16x32_bf16(a[i], b[j], acc[i][j], 0, 0, 0);
#pragma unroll
        for (int i = 0; i < 4; ++i)
            a[i] = *(const short8*)&As1[(wm * 64 + i * 16 + l16) * 32 + quad * 8];
#pragma unroll
        for (int j = 0; j < 4; ++j)
            b[j] = *(const short8*)&Bs1[(wn * 64 + j * 16 + l16) * 32 + quad * 8];
#pragma unroll
        for (int i = 0; i < 4; ++i)
#pragma unroll
            for (int j = 0; j < 4; ++j)
                acc[i][j] = __builtin_amdgcn_mfma_f32_16x16x32_bf16(a[i], b[j], acc[i][j], 0, 0, 0);
    }

#pragma unroll
    for (int i = 0; i < 4; ++i) {
        float invl[4];
#pragma unroll
        for (int r = 0; r < 4; ++r)
            invl[r] = 1.0f / lsum[q0 + wm * 64 + i * 16 + quad * 4 + r];
#pragma unroll
        for (int j = 0; j < 4; ++j) {
#pragma unroll
            for (int r = 0; r < 4; ++r) {
                int qrow = q0 + wm * 64 + i * 16 + quad * 4 + r;
                int dcol = d0 + wn * 64 + j * 16 + l16;
                atomicAdd(&out[(size_t)qrow * DIM + dcol], acc[i][j][r] * invl[r]);
            }
        }
    }
}

// ---------------------------------------------------------------------------
// Path D fallback (ws too small) — correct but slow.
// ---------------------------------------------------------------------------
__global__ void fused_fallback(const float* __restrict__ Q,
                               const float* __restrict__ K,
                               float* __restrict__ out) {
    int wave = threadIdx.x >> 6, lane = threadIdx.x & 63;
    int q0 = blockIdx.x * 16 + wave * 4;
    float qv[4][16], acc[4][16], iqn[4], ls[4];
#pragma unroll
    for (int r = 0; r < 4; ++r) {
        float s = 0.f;
#pragma unroll
        for (int c = 0; c < 4; ++c) {
            float4 f = *(const float4*)(Q + (size_t)(q0 + r) * DIM + c * 256 + lane * 4);
            qv[r][c * 4 + 0] = f.x; qv[r][c * 4 + 1] = f.y;
            qv[r][c * 4 + 2] = f.z; qv[r][c * 4 + 3] = f.w;
            s += f.x * f.x + f.y * f.y + f.z * f.z + f.w * f.w;
        }
#pragma unroll
        for (int off = 32; off > 0; off >>= 1) s += __shfl_xor(s, off);
        iqn[r] = 1.0f / sqrtf(s);
        ls[r] = 0.f;
#pragma unroll
        for (int t = 0; t < 16; ++t) acc[r][t] = 0.f;
    }
    for (int k = 0; k < NK; ++k) {
        const float* kr = K + (size_t)k * DIM;
        float kv[16], ss = 0.f;
#pragma unroll
        for (int c = 0; c < 4; ++c) {
            float4 f = *(const float4*)(kr + c * 256 + lane * 4);
            kv[c * 4 + 0] = f.x; kv[c * 4 + 1] = f.y;
            kv[c * 4 + 2] = f.z; kv[c * 4 + 3] = f.w;
            ss += f.x * f.x + f.y * f.y + f.z * f.z + f.w * f.w;
        }
        float d0 = 0.f, d1 = 0.f, d2 = 0.f, d3 = 0.f;
#pragma unroll
        for (int t = 0; t < 16; ++t) {
            d0 += qv[0][t] * kv[t]; d1 += qv[1][t] * kv[t];
            d2 += qv[2][t] * kv[t]; d3 += qv[3][t] * kv[t];
        }
#pragma unroll
        for (int off = 32; off > 0; off >>= 1) {
            ss += __shfl_xor(ss, off);
            d0 += __shfl_xor(d0, off); d1 += __shfl_xor(d1, off);
            d2 += __shfl_xor(d2, off); d3 += __shfl_xor(d3, off);
        }
        float ikn = 1.0f / sqrtf(ss);
        float p0 = __expf(d0 * iqn[0] * ikn), p1 = __expf(d1 * iqn[1] * ikn);
        float p2 = __expf(d2 * iqn[2] * ikn), p3 = __expf(d3 * iqn[3] * ikn);
        ls[0] += p0; ls[1] += p1; ls[2] += p2; ls[3] += p3;
#pragma unroll
        for (int t = 0; t < 16; ++t) {
            acc[0][t] += p0 * kv[t]; acc[1][t] += p1 * kv[t];
            acc[2][t] += p2 * kv[t]; acc[3][t] += p3 * kv[t];
        }
    }
#pragma unroll
    for (int r = 0; r < 4; ++r) {
        float inv = 1.0f / ls[r];
#pragma unroll
        for (int c = 0; c < 4; ++c) {
            float4 o;
            o.x = acc[r][c * 4 + 0] * inv; o.y = acc[r][c * 4 + 1] * inv;
            o.z = acc[r][c * 4 + 2] * inv; o.w = acc[r][c * 4 + 3] * inv;
            *(float4*)(out + (size_t)(q0 + r) * DIM + c * 256 + lane * 4) = o;
        }
    }
}

// ---------------------------------------------------------------------------
// launch — ws layout: Kt [0,16M) overlaps Qb/Kb (dead after score_gemm);
// P [24M,88M); inv_qn/inv_kn/lsum at 88M.
// ---------------------------------------------------------------------------
extern "C" void kernel_launch(void* const* d_in, const int* in_sizes, int n_in,
                              void* d_out, int out_size, void* d_ws, size_t ws_size,
                              hipStream_t stream) {
    const float* Q = (const float*)d_in[0];
    const float* K = (const float*)d_in[1];
    float* out = (float*)d_out;
    char* ws = (char*)d_ws;

    const size_t REQ_A = ((size_t)88u << 20) + 65536;
    if (ws_size >= REQ_A) {
        unsigned short* Kt = (unsigned short*)(ws);
        unsigned short* Qb = (unsigned short*)(ws);
        unsigned short* Kb = (unsigned short*)(ws + (size_t)(8u << 20));
        unsigned short* P  = (unsigned short*)(ws + (size_t)(24u << 20));
        float* inv_qn = (float*)(ws + (size_t)(88u << 20));
        float* inv_kn = (float*)(ws + (size_t)(88u << 20) + 16384);
        float* lsum   = (float*)(ws + (size_t)(88u << 20) + 49152);

        prep_q_zero<<<NQ / 4, 256, 0, stream>>>(Q, Qb, inv_qn, lsum, out);
        prep_norm_cvt<<<NK / 4, 256, 0, stream>>>(K, Kb, inv_kn);
        score_gemm<<<2048, 256, 0, stream>>>(Qb, Kb, inv_qn, inv_kn, P, lsum);
        transpose_cvt<<<dim3(NK / 64, DIM / 64), 256, 0, stream>>>(K, Kt);
        ctx_gemm<<<1024, 256, 0, stream>>>(P, Kt, lsum, out);
    } else {
        fused_fallback<<<NQ / 16, 256, 0, stream>>>(Q, K, out);
    }
}

// Round 10
// 317.951 us; speedup vs baseline: 1.8867x; 1.0013x over previous
//
// R10: score = R9 (BK64 + q-tile-per-XCD swizzle); ctx = R7 (BK32, split-K x4
// + XCD swizzle); BOTH get XOR LDS column swizzle to kill the measured 8-way
// bank conflicts (8.39M cycles/dispatch): chunk c of row r stored at column
// c ^ ((r>>1)&3); 2-way residual aliasing is free (m136).
#include <hip/hip_runtime.h>

#define NQ 4096
#define NK 8192
#define DIM 1024

typedef __attribute__((ext_vector_type(8))) short short8;
typedef __attribute__((ext_vector_type(4))) float floatx4;
typedef unsigned int u32;
typedef __attribute__((address_space(3))) u32 lds_u32;
typedef __attribute__((address_space(1))) const u32 glb_u32;

__device__ __forceinline__ void gload_lds16(const void* g, void* l) {
    __builtin_amdgcn_global_load_lds((glb_u32*)g, (lds_u32*)l, 16, 0, 0);
}

__device__ __forceinline__ unsigned short f32_bf16(float f) {
    unsigned int u = __float_as_uint(f);
    u += 0x7fff + ((u >> 16) & 1);
    return (unsigned short)(u >> 16);
}

// ---------------------------------------------------------------------------
// Q prep + zero(out) + zero(lsum)
// ---------------------------------------------------------------------------
__global__ void prep_q_zero(const float* __restrict__ Q,
                            unsigned short* __restrict__ Qb,
                            float* __restrict__ inv_qn,
                            float* __restrict__ lsum,
                            float* __restrict__ out) {
    int wave = threadIdx.x >> 6;
    int lane = threadIdx.x & 63;
    int row  = blockIdx.x * 4 + wave;
    const float* r = Q + (size_t)row * DIM;
    float s = 0.f;
#pragma unroll
    for (int c = 0; c < 4; ++c) {
        float4 f = *(const float4*)(r + c * 256 + lane * 4);
        s += f.x * f.x + f.y * f.y + f.z * f.z + f.w * f.w;
        ushort4 b;
        b.x = f32_bf16(f.x); b.y = f32_bf16(f.y);
        b.z = f32_bf16(f.z); b.w = f32_bf16(f.w);
        *(ushort4*)(Qb + (size_t)row * DIM + c * 256 + lane * 4) = b;
    }
#pragma unroll
    for (int off = 32; off > 0; off >>= 1) s += __shfl_xor(s, off);
    if (lane == 0) inv_qn[row] = 1.0f / sqrtf(s);

    float4 z = make_float4(0.f, 0.f, 0.f, 0.f);
#pragma unroll
    for (int c = 0; c < 4; ++c)
        *(float4*)(out + (size_t)blockIdx.x * 4096 + c * 1024 + threadIdx.x * 4) = z;
    if (blockIdx.x < 4)
        *(float4*)(lsum + blockIdx.x * 1024 + threadIdx.x * 4) = z;
}

// ---------------------------------------------------------------------------
// K prep: bf16 convert + 1/norm
// ---------------------------------------------------------------------------
__global__ void prep_norm_cvt(const float* __restrict__ src,
                              unsigned short* __restrict__ dst,
                              float* __restrict__ inv_norm) {
    int wave = threadIdx.x >> 6;
    int lane = threadIdx.x & 63;
    int row  = blockIdx.x * 4 + wave;
    const float* r = src + (size_t)row * DIM;
    float s = 0.f;
#pragma unroll
    for (int c = 0; c < 4; ++c) {
        float4 f = *(const float4*)(r + c * 256 + lane * 4);
        s += f.x * f.x + f.y * f.y + f.z * f.z + f.w * f.w;
        ushort4 b;
        b.x = f32_bf16(f.x); b.y = f32_bf16(f.y);
        b.z = f32_bf16(f.z); b.w = f32_bf16(f.w);
        *(ushort4*)(dst + (size_t)row * DIM + c * 256 + lane * 4) = b;
    }
#pragma unroll
    for (int off = 32; off > 0; off >>= 1) s += __shfl_xor(s, off);
    if (lane == 0) inv_norm[row] = 1.0f / sqrtf(s);
}

// ---------------------------------------------------------------------------
// transpose + convert: Kt[d][kn] = bf16(K[kn][d])
// ---------------------------------------------------------------------------
__global__ void transpose_cvt(const float* __restrict__ K,
                              unsigned short* __restrict__ Kt) {
    __shared__ float t[64][65];
    int kn0 = blockIdx.x * 64, d0 = blockIdx.y * 64;
    int tid = threadIdx.x;
    int r  = tid >> 4;
    int c4 = (tid & 15) * 4;
#pragma unroll
    for (int s = 0; s < 4; ++s) {
        int kk = s * 16 + r;
        float4 f = *(const float4*)(K + (size_t)(kn0 + kk) * DIM + d0 + c4);
        t[kk][c4 + 0] = f.x; t[kk][c4 + 1] = f.y;
        t[kk][c4 + 2] = f.z; t[kk][c4 + 3] = f.w;
    }
    __syncthreads();
#pragma unroll
    for (int s = 0; s < 4; ++s) {
        int dd = s * 16 + r;
        ushort4 b;
        b.x = f32_bf16(t[c4 + 0][dd]);
        b.y = f32_bf16(t[c4 + 1][dd]);
        b.z = f32_bf16(t[c4 + 2][dd]);
        b.w = f32_bf16(t[c4 + 3][dd]);
        *(ushort4*)(Kt + (size_t)(d0 + dd) * NK + kn0 + c4) = b;
    }
}

// ---------------------------------------------------------------------------
// GEMM 1: BK=64 dual panels, q-tile-per-XCD swizzle, XOR LDS swizzle.
// ---------------------------------------------------------------------------
__global__ void score_gemm(const unsigned short* __restrict__ Qb,
                           const unsigned short* __restrict__ Kb,
                           const float* __restrict__ inv_qn,
                           const float* __restrict__ inv_kn,
                           unsigned short* __restrict__ P,
                           float* __restrict__ lsum) {
    __shared__ __align__(16) unsigned short As0[128 * 32];
    __shared__ __align__(16) unsigned short As1[128 * 32];
    __shared__ __align__(16) unsigned short Bs0[128 * 32];
    __shared__ __align__(16) unsigned short Bs1[128 * 32];

    int id  = blockIdx.x;
    int r8  = id & 7;
    int t   = id >> 3;
    int n   = t & 63;
    int qhi = t >> 6;              // 0..3
    int q0  = (qhi * 8 + r8) * 128;
    int n0  = n * 128;

    int tid = threadIdx.x;
    int wave = tid >> 6, lane = tid & 63;
    int wm = wave >> 1, wn = wave & 1;
    int quad = lane >> 4, l16 = lane & 15;

    // staging: lane l covers row srow, fetches global chunk (l&3)^((l>>3)&3)
    // so that LDS physical col p of row r holds chunk p^((r>>1)&3).
    int srow   = wave * 32 + (lane >> 2);
    int schunk = (((lane & 3) ^ ((lane >> 3) & 3))) * 8;
    const unsigned short* gA = Qb + (size_t)(q0 + srow) * DIM + schunk;
    const unsigned short* gB = Kb + (size_t)(n0 + srow) * DIM + schunk;
    unsigned short* lA0 = As0 + wave * 32 * 32;
    unsigned short* lA1 = As1 + wave * 32 * 32;
    unsigned short* lB0 = Bs0 + wave * 32 * 32;
    unsigned short* lB1 = Bs1 + wave * 32 * 32;

    // frag read: logical chunk quad of row (i*16+l16) is at col quad^((l16>>1)&3)
    int rcol = (quad ^ ((l16 >> 1) & 3)) * 8;

    floatx4 acc[4][4];
#pragma unroll
    for (int i = 0; i < 4; ++i)
#pragma unroll
        for (int j = 0; j < 4; ++j) acc[i][j] = (floatx4)(0.0f);

    for (int kb = 0; kb < DIM / 64; ++kb) {
        int d0 = kb * 64;
        __syncthreads();
        gload_lds16(gA + d0, lA0);
        gload_lds16(gA + (size_t)16 * DIM + d0, lA0 + 16 * 32);
        gload_lds16(gA + d0 + 32, lA1);
        gload_lds16(gA + (size_t)16 * DIM + d0 + 32, lA1 + 16 * 32);
        gload_lds16(gB + d0, lB0);
        gload_lds16(gB + (size_t)16 * DIM + d0, lB0 + 16 * 32);
        gload_lds16(gB + d0 + 32, lB1);
        gload_lds16(gB + (size_t)16 * DIM + d0 + 32, lB1 + 16 * 32);
        __syncthreads();
        short8 a[4], b[4];
#pragma unroll
        for (int i = 0; i < 4; ++i)
            a[i] = *(const short8*)&As0[(wm * 64 + i * 16 + l16) * 32 + rcol];
#pragma unroll
        for (int j = 0; j < 4; ++j)
            b[j] = *(const short8*)&Bs0[(wn * 64 + j * 16 + l16) * 32 + rcol];
#pragma unroll
        for (int i = 0; i < 4; ++i)
#pragma unroll
            for (int j = 0; j < 4; ++j)
                acc[i][j] = __builtin_amdgcn_mfma_f32_16x16x32_bf16(b[j], a[i], acc[i][j], 0, 0, 0);
#pragma unroll
        for (int i = 0; i < 4; ++i)
            a[i] = *(const short8*)&As1[(wm * 64 + i * 16 + l16) * 32 + rcol];
#pragma unroll
        for (int j = 0; j < 4; ++j)
            b[j] = *(const short8*)&Bs1[(wn * 64 + j * 16 + l16) * 32 + rcol];
#pragma unroll
        for (int i = 0; i < 4; ++i)
#pragma unroll
            for (int j = 0; j < 4; ++j)
                acc[i][j] = __builtin_amdgcn_mfma_f32_16x16x32_bf16(b[j], a[i], acc[i][j], 0, 0, 0);
    }

#pragma unroll
    for (int i = 0; i < 4; ++i) {
        int qrow = q0 + wm * 64 + i * 16 + l16;
        float iqn = inv_qn[qrow];
        float rs = 0.f;
#pragma unroll
        for (int j = 0; j < 4; ++j) {
            int ncol = n0 + wn * 64 + j * 16 + quad * 4;
            float4 ik = *(const float4*)&inv_kn[ncol];
            float p0 = __expf(acc[i][j][0] * iqn * ik.x);
            float p1 = __expf(acc[i][j][1] * iqn * ik.y);
            float p2 = __expf(acc[i][j][2] * iqn * ik.z);
            float p3 = __expf(acc[i][j][3] * iqn * ik.w);
            ushort4 pb;
            pb.x = f32_bf16(p0); pb.y = f32_bf16(p1);
            pb.z = f32_bf16(p2); pb.w = f32_bf16(p3);
            *(ushort4*)&P[(size_t)qrow * NK + ncol] = pb;
            rs += p0 + p1 + p2 + p3;
        }
        rs += __shfl_xor(rs, 16);
        rs += __shfl_xor(rs, 32);
        if (quad == 0) atomicAdd(&lsum[qrow], rs);
    }
}

// ---------------------------------------------------------------------------
// GEMM 2: R7 config (BK=32, split-K x4 + XCD swizzle) + XOR LDS swizzle.
// ---------------------------------------------------------------------------
__global__ void ctx_gemm(const unsigned short* __restrict__ P,
                         const unsigned short* __restrict__ Kt,
                         const float* __restrict__ lsum,
                         float* __restrict__ out) {
    __shared__ __align__(16) unsigned short As[128 * 32];
    __shared__ __align__(16) unsigned short Bs[128 * 32];
    int id = blockIdx.x;
    int r8 = id & 7;
    int t  = id >> 3;
    int x  = t & 7;
    int g  = ((t >> 3) << 3) | r8;   // 0..127
    int y  = g & 31;
    int z  = g >> 5;                 // 0..3
    int q0 = y * 128;
    int d0 = x * 128;
    int kbase = z * (NK / 4);

    int tid = threadIdx.x;
    int wave = tid >> 6, lane = tid & 63;
    int wm = wave >> 1, wn = wave & 1;
    int quad = lane >> 4, l16 = lane & 15;

    int srow   = wave * 32 + (lane >> 2);
    int schunk = (((lane & 3) ^ ((lane >> 3) & 3))) * 8;
    const unsigned short* gA0 = P + (size_t)(q0 + srow) * NK + kbase + schunk;
    const unsigned short* gA1 = gA0 + (size_t)16 * NK;
    const unsigned short* gB0 = Kt + (size_t)(d0 + srow) * NK + kbase + schunk;
    const unsigned short* gB1 = gB0 + (size_t)16 * NK;
    unsigned short* lA0 = As + wave * 32 * 32;
    unsigned short* lA1 = lA0 + 16 * 32;
    unsigned short* lB0 = Bs + wave * 32 * 32;
    unsigned short* lB1 = lB0 + 16 * 32;

    int rcol = (quad ^ ((l16 >> 1) & 3)) * 8;

    floatx4 acc[4][4];
#pragma unroll
    for (int i = 0; i < 4; ++i)
#pragma unroll
        for (int j = 0; j < 4; ++j) acc[i][j] = (floatx4)(0.0f);

    for (int kb = 0; kb < (NK / 4) / 32; ++kb) {
        int k0 = kb * 32;
        __syncthreads();
        gload_lds16(gA0 + k0, lA0);
        gload_lds16(gA1 + k0, lA1);
        gload_lds16(gB0 + k0, lB0);
        gload_lds16(gB1 + k0, lB1);
        __syncthreads();
        short8 a[4], b[4];
#pragma unroll
        for (int i = 0; i < 4; ++i)
            a[i] = *(const short8*)&As[(wm * 64 + i * 16 + l16) * 32 + rcol];
#pragma unroll
        for (int j = 0; j < 4; ++j)
            b[j] = *(const short8*)&Bs[(wn * 64 + j * 16 + l16) * 32 + rcol];
#pragma unroll
        for (int i = 0; i < 4; ++i)
#pragma unroll
            for (int j = 0; j < 4; ++j)
                acc[i][j] = __builtin_amdgcn_mfma_f32_16x16x32_bf16(a[i], b[j], acc[i][j], 0, 0, 0);
    }

#pragma unroll
    for (int i = 0; i < 4; ++i) {
        float invl[4];
#pragma unroll
        for (int r = 0; r < 4; ++r)
            invl[r] = 1.0f / lsum[q0 + wm * 64 + i * 16 + quad * 4 + r];
#pragma unroll
        for (int j = 0; j < 4; ++j) {
#pragma unroll
            for (int r = 0; r < 4; ++r) {
                int qrow = q0 + wm * 64 + i * 16 + quad * 4 + r;
                int dcol = d0 + wn * 64 + j * 16 + l16;
                atomicAdd(&out[(size_t)qrow * DIM + dcol], acc[i][j][r] * invl[r]);
            }
        }
    }
}

// ---------------------------------------------------------------------------
// Path D fallback (ws too small) — correct but slow.
// ---------------------------------------------------------------------------
__global__ void fused_fallback(const float* __restrict__ Q,
                               const float* __restrict__ K,
                               float* __restrict__ out) {
    int wave = threadIdx.x >> 6, lane = threadIdx.x & 63;
    int q0 = blockIdx.x * 16 + wave * 4;
    float qv[4][16], acc[4][16], iqn[4], ls[4];
#pragma unroll
    for (int r = 0; r < 4; ++r) {
        float s = 0.f;
#pragma unroll
        for (int c = 0; c < 4; ++c) {
            float4 f = *(const float4*)(Q + (size_t)(q0 + r) * DIM + c * 256 + lane * 4);
            qv[r][c * 4 + 0] = f.x; qv[r][c * 4 + 1] = f.y;
            qv[r][c * 4 + 2] = f.z; qv[r][c * 4 + 3] = f.w;
            s += f.x * f.x + f.y * f.y + f.z * f.z + f.w * f.w;
        }
#pragma unroll
        for (int off = 32; off > 0; off >>= 1) s += __shfl_xor(s, off);
        iqn[r] = 1.0f / sqrtf(s);
        ls[r] = 0.f;
#pragma unroll
        for (int t = 0; t < 16; ++t) acc[r][t] = 0.f;
    }
    for (int k = 0; k < NK; ++k) {
        const float* kr = K + (size_t)k * DIM;
        float kv[16], ss = 0.f;
#pragma unroll
        for (int c = 0; c < 4; ++c) {
            float4 f = *(const float4*)(kr + c * 256 + lane * 4);
            kv[c * 4 + 0] = f.x; kv[c * 4 + 1] = f.y;
            kv[c * 4 + 2] = f.z; kv[c * 4 + 3] = f.w;
            ss += f.x * f.x + f.y * f.y + f.z * f.z + f.w * f.w;
        }
        float d0 = 0.f, d1 = 0.f, d2 = 0.f, d3 = 0.f;
#pragma unroll
        for (int t = 0; t < 16; ++t) {
            d0 += qv[0][t] * kv[t]; d1 += qv[1][t] * kv[t];
            d2 += qv[2][t] * kv[t]; d3 += qv[3][t] * kv[t];
        }
#pragma unroll
        for (int off = 32; off > 0; off >>= 1) {
            ss += __shfl_xor(ss, off);
            d0 += __shfl_xor(d0, off); d1 += __shfl_xor(d1, off);
            d2 += __shfl_xor(d2, off); d3 += __shfl_xor(d3, off);
        }
        float ikn = 1.0f / sqrtf(ss);
        float p0 = __expf(d0 * iqn[0] * ikn), p1 = __expf(d1 * iqn[1] * ikn);
        float p2 = __expf(d2 * iqn[2] * ikn), p3 = __expf(d3 * iqn[3] * ikn);
        ls[0] += p0; ls[1] += p1; ls[2] += p2; ls[3] += p3;
#pragma unroll
        for (int t = 0; t < 16; ++t) {
            acc[0][t] += p0 * kv[t]; acc[1][t] += p1 * kv[t];
            acc[2][t] += p2 * kv[t]; acc[3][t] += p3 * kv[t];
        }
    }
#pragma unroll
    for (int r = 0; r < 4; ++r) {
        float inv = 1.0f / ls[r];
#pragma unroll
        for (int c = 0; c < 4; ++c) {
            float4 o;
            o.x = acc[r][c * 4 + 0] * inv; o.y = acc[r][c * 4 + 1] * inv;
            o.z = acc[r][c * 4 + 2] * inv; o.w = acc[r][c * 4 + 3] * inv;
            *(float4*)(out + (size_t)(q0 + r) * DIM + c * 256 + lane * 4) = o;
        }
    }
}

// ---------------------------------------------------------------------------
// launch — ws layout: Kt [0,16M) overlaps Qb/Kb (dead after score_gemm);
// P [24M,88M); inv_qn/inv_kn/lsum at 88M.
// ---------------------------------------------------------------------------
extern "C" void kernel_launch(void* const* d_in, const int* in_sizes, int n_in,
                              void* d_out, int out_size, void* d_ws, size_t ws_size,
                              hipStream_t stream) {
    const float* Q = (const float*)d_in[0];
    const float* K = (const float*)d_in[1];
    float* out = (float*)d_out;
    char* ws = (char*)d_ws;

    const size_t REQ_A = ((size_t)88u << 20) + 65536;
    if (ws_size >= REQ_A) {
        unsigned short* Kt = (unsigned short*)(ws);
        unsigned short* Qb = (unsigned short*)(ws);
        unsigned short* Kb = (unsigned short*)(ws + (size_t)(8u << 20));
        unsigned short* P  = (unsigned short*)(ws + (size_t)(24u << 20));
        float* inv_qn = (float*)(ws + (size_t)(88u << 20));
        float* inv_kn = (float*)(ws + (size_t)(88u << 20) + 16384);
        float* lsum   = (float*)(ws + (size_t)(88u << 20) + 49152);

        prep_q_zero<<<NQ / 4, 256, 0, stream>>>(Q, Qb, inv_qn, lsum, out);
        prep_norm_cvt<<<NK / 4, 256, 0, stream>>>(K, Kb, inv_kn);
        score_gemm<<<2048, 256, 0, stream>>>(Qb, Kb, inv_qn, inv_kn, P, lsum);
        transpose_cvt<<<dim3(NK / 64, DIM / 64), 256, 0, stream>>>(K, Kt);
        ctx_gemm<<<1024, 256, 0, stream>>>(P, Kt, lsum, out);
    } else {
        fused_fallback<<<NQ / 16, 256, 0, stream>>>(Q, K, out);
    }
}

// Round 11
// 300.620 us; speedup vs baseline: 1.9955x; 1.0577x over previous
//
// R11: ctx atomics -> plain partial stores (operand-swapped, float4) + reduce
// kernel. 3-tier ws dispatch: >=152M new path; >=88M exact-R10; else fallback.
#include <hip/hip_runtime.h>

#define NQ 4096
#define NK 8192
#define DIM 1024

typedef __attribute__((ext_vector_type(8))) short short8;
typedef __attribute__((ext_vector_type(4))) float floatx4;
typedef unsigned int u32;
typedef __attribute__((address_space(3))) u32 lds_u32;
typedef __attribute__((address_space(1))) const u32 glb_u32;

__device__ __forceinline__ void gload_lds16(const void* g, void* l) {
    __builtin_amdgcn_global_load_lds((glb_u32*)g, (lds_u32*)l, 16, 0, 0);
}

__device__ __forceinline__ unsigned short f32_bf16(float f) {
    unsigned int u = __float_as_uint(f);
    u += 0x7fff + ((u >> 16) & 1);
    return (unsigned short)(u >> 16);
}

// ---------------------------------------------------------------------------
// Q prep + optional zero(out) + zero(lsum)
// ---------------------------------------------------------------------------
__global__ void prep_q_zero(const float* __restrict__ Q,
                            unsigned short* __restrict__ Qb,
                            float* __restrict__ inv_qn,
                            float* __restrict__ lsum,
                            float* __restrict__ out_zero) {
    int wave = threadIdx.x >> 6;
    int lane = threadIdx.x & 63;
    int row  = blockIdx.x * 4 + wave;
    const float* r = Q + (size_t)row * DIM;
    float s = 0.f;
#pragma unroll
    for (int c = 0; c < 4; ++c) {
        float4 f = *(const float4*)(r + c * 256 + lane * 4);
        s += f.x * f.x + f.y * f.y + f.z * f.z + f.w * f.w;
        ushort4 b;
        b.x = f32_bf16(f.x); b.y = f32_bf16(f.y);
        b.z = f32_bf16(f.z); b.w = f32_bf16(f.w);
        *(ushort4*)(Qb + (size_t)row * DIM + c * 256 + lane * 4) = b;
    }
#pragma unroll
    for (int off = 32; off > 0; off >>= 1) s += __shfl_xor(s, off);
    if (lane == 0) inv_qn[row] = 1.0f / sqrtf(s);

    float4 z = make_float4(0.f, 0.f, 0.f, 0.f);
    if (out_zero) {
#pragma unroll
        for (int c = 0; c < 4; ++c)
            *(float4*)(out_zero + (size_t)blockIdx.x * 4096 + c * 1024 + threadIdx.x * 4) = z;
    }
    if (blockIdx.x < 4)
        *(float4*)(lsum + blockIdx.x * 1024 + threadIdx.x * 4) = z;
}

// ---------------------------------------------------------------------------
// K prep: bf16 convert + 1/norm
// ---------------------------------------------------------------------------
__global__ void prep_norm_cvt(const float* __restrict__ src,
                              unsigned short* __restrict__ dst,
                              float* __restrict__ inv_norm) {
    int wave = threadIdx.x >> 6;
    int lane = threadIdx.x & 63;
    int row  = blockIdx.x * 4 + wave;
    const float* r = src + (size_t)row * DIM;
    float s = 0.f;
#pragma unroll
    for (int c = 0; c < 4; ++c) {
        float4 f = *(const float4*)(r + c * 256 + lane * 4);
        s += f.x * f.x + f.y * f.y + f.z * f.z + f.w * f.w;
        ushort4 b;
        b.x = f32_bf16(f.x); b.y = f32_bf16(f.y);
        b.z = f32_bf16(f.z); b.w = f32_bf16(f.w);
        *(ushort4*)(dst + (size_t)row * DIM + c * 256 + lane * 4) = b;
    }
#pragma unroll
    for (int off = 32; off > 0; off >>= 1) s += __shfl_xor(s, off);
    if (lane == 0) inv_norm[row] = 1.0f / sqrtf(s);
}

// ---------------------------------------------------------------------------
// transpose + convert: Kt[d][kn] = bf16(K[kn][d])
// ---------------------------------------------------------------------------
__global__ void transpose_cvt(const float* __restrict__ K,
                              unsigned short* __restrict__ Kt) {
    __shared__ float t[64][65];
    int kn0 = blockIdx.x * 64, d0 = blockIdx.y * 64;
    int tid = threadIdx.x;
    int r  = tid >> 4;
    int c4 = (tid & 15) * 4;
#pragma unroll
    for (int s = 0; s < 4; ++s) {
        int kk = s * 16 + r;
        float4 f = *(const float4*)(K + (size_t)(kn0 + kk) * DIM + d0 + c4);
        t[kk][c4 + 0] = f.x; t[kk][c4 + 1] = f.y;
        t[kk][c4 + 2] = f.z; t[kk][c4 + 3] = f.w;
    }
    __syncthreads();
#pragma unroll
    for (int s = 0; s < 4; ++s) {
        int dd = s * 16 + r;
        ushort4 b;
        b.x = f32_bf16(t[c4 + 0][dd]);
        b.y = f32_bf16(t[c4 + 1][dd]);
        b.z = f32_bf16(t[c4 + 2][dd]);
        b.w = f32_bf16(t[c4 + 3][dd]);
        *(ushort4*)(Kt + (size_t)(d0 + dd) * NK + kn0 + c4) = b;
    }
}

// ---------------------------------------------------------------------------
// GEMM 1: BK=64 dual panels, q-tile-per-XCD swizzle, XOR LDS swizzle (R10).
// ---------------------------------------------------------------------------
__global__ void score_gemm(const unsigned short* __restrict__ Qb,
                           const unsigned short* __restrict__ Kb,
                           const float* __restrict__ inv_qn,
                           const float* __restrict__ inv_kn,
                           unsigned short* __restrict__ P,
                           float* __restrict__ lsum) {
    __shared__ __align__(16) unsigned short As0[128 * 32];
    __shared__ __align__(16) unsigned short As1[128 * 32];
    __shared__ __align__(16) unsigned short Bs0[128 * 32];
    __shared__ __align__(16) unsigned short Bs1[128 * 32];

    int id  = blockIdx.x;
    int r8  = id & 7;
    int t   = id >> 3;
    int n   = t & 63;
    int qhi = t >> 6;
    int q0  = (qhi * 8 + r8) * 128;
    int n0  = n * 128;

    int tid = threadIdx.x;
    int wave = tid >> 6, lane = tid & 63;
    int wm = wave >> 1, wn = wave & 1;
    int quad = lane >> 4, l16 = lane & 15;

    int srow   = wave * 32 + (lane >> 2);
    int schunk = (((lane & 3) ^ ((lane >> 3) & 3))) * 8;
    const unsigned short* gA = Qb + (size_t)(q0 + srow) * DIM + schunk;
    const unsigned short* gB = Kb + (size_t)(n0 + srow) * DIM + schunk;
    unsigned short* lA0 = As0 + wave * 32 * 32;
    unsigned short* lA1 = As1 + wave * 32 * 32;
    unsigned short* lB0 = Bs0 + wave * 32 * 32;
    unsigned short* lB1 = Bs1 + wave * 32 * 32;

    int rcol = (quad ^ ((l16 >> 1) & 3)) * 8;

    floatx4 acc[4][4];
#pragma unroll
    for (int i = 0; i < 4; ++i)
#pragma unroll
        for (int j = 0; j < 4; ++j) acc[i][j] = (floatx4)(0.0f);

    for (int kb = 0; kb < DIM / 64; ++kb) {
        int d0 = kb * 64;
        __syncthreads();
        gload_lds16(gA + d0, lA0);
        gload_lds16(gA + (size_t)16 * DIM + d0, lA0 + 16 * 32);
        gload_lds16(gA + d0 + 32, lA1);
        gload_lds16(gA + (size_t)16 * DIM + d0 + 32, lA1 + 16 * 32);
        gload_lds16(gB + d0, lB0);
        gload_lds16(gB + (size_t)16 * DIM + d0, lB0 + 16 * 32);
        gload_lds16(gB + d0 + 32, lB1);
        gload_lds16(gB + (size_t)16 * DIM + d0 + 32, lB1 + 16 * 32);
        __syncthreads();
        short8 a[4], b[4];
#pragma unroll
        for (int i = 0; i < 4; ++i)
            a[i] = *(const short8*)&As0[(wm * 64 + i * 16 + l16) * 32 + rcol];
#pragma unroll
        for (int j = 0; j < 4; ++j)
            b[j] = *(const short8*)&Bs0[(wn * 64 + j * 16 + l16) * 32 + rcol];
#pragma unroll
        for (int i = 0; i < 4; ++i)
#pragma unroll
            for (int j = 0; j < 4; ++j)
                acc[i][j] = __builtin_amdgcn_mfma_f32_16x16x32_bf16(b[j], a[i], acc[i][j], 0, 0, 0);
#pragma unroll
        for (int i = 0; i < 4; ++i)
            a[i] = *(const short8*)&As1[(wm * 64 + i * 16 + l16) * 32 + rcol];
#pragma unroll
        for (int j = 0; j < 4; ++j)
            b[j] = *(const short8*)&Bs1[(wn * 64 + j * 16 + l16) * 32 + rcol];
#pragma unroll
        for (int i = 0; i < 4; ++i)
#pragma unroll
            for (int j = 0; j < 4; ++j)
                acc[i][j] = __builtin_amdgcn_mfma_f32_16x16x32_bf16(b[j], a[i], acc[i][j], 0, 0, 0);
    }

#pragma unroll
    for (int i = 0; i < 4; ++i) {
        int qrow = q0 + wm * 64 + i * 16 + l16;
        float iqn = inv_qn[qrow];
        float rs = 0.f;
#pragma unroll
        for (int j = 0; j < 4; ++j) {
            int ncol = n0 + wn * 64 + j * 16 + quad * 4;
            float4 ik = *(const float4*)&inv_kn[ncol];
            float p0 = __expf(acc[i][j][0] * iqn * ik.x);
            float p1 = __expf(acc[i][j][1] * iqn * ik.y);
            float p2 = __expf(acc[i][j][2] * iqn * ik.z);
            float p3 = __expf(acc[i][j][3] * iqn * ik.w);
            ushort4 pb;
            pb.x = f32_bf16(p0); pb.y = f32_bf16(p1);
            pb.z = f32_bf16(p2); pb.w = f32_bf16(p3);
            *(ushort4*)&P[(size_t)qrow * NK + ncol] = pb;
            rs += p0 + p1 + p2 + p3;
        }
        rs += __shfl_xor(rs, 16);
        rs += __shfl_xor(rs, 32);
        if (quad == 0) atomicAdd(&lsum[qrow], rs);
    }
}

// ---------------------------------------------------------------------------
// GEMM 2 tier-1: split-K x4 + XCD swizzle, XOR LDS swizzle, OPERAND-SWAPPED,
// plain float4 partial stores into part[z][q][d] (no atomics, no lsum).
// ---------------------------------------------------------------------------
__global__ void ctx_gemm_st(const unsigned short* __restrict__ P,
                            const unsigned short* __restrict__ Kt,
                            float* __restrict__ part) {
    __shared__ __align__(16) unsigned short As[128 * 32];
    __shared__ __align__(16) unsigned short Bs[128 * 32];
    int id = blockIdx.x;
    int r8 = id & 7;
    int t  = id >> 3;
    int x  = t & 7;
    int g  = ((t >> 3) << 3) | r8;   // 0..127
    int y  = g & 31;
    int z  = g >> 5;                 // 0..3
    int q0 = y * 128;
    int d0 = x * 128;
    int kbase = z * (NK / 4);

    int tid = threadIdx.x;
    int wave = tid >> 6, lane = tid & 63;
    int wm = wave >> 1, wn = wave & 1;
    int quad = lane >> 4, l16 = lane & 15;

    int srow   = wave * 32 + (lane >> 2);
    int schunk = (((lane & 3) ^ ((lane >> 3) & 3))) * 8;
    const unsigned short* gA0 = P + (size_t)(q0 + srow) * NK + kbase + schunk;
    const unsigned short* gA1 = gA0 + (size_t)16 * NK;
    const unsigned short* gB0 = Kt + (size_t)(d0 + srow) * NK + kbase + schunk;
    const unsigned short* gB1 = gB0 + (size_t)16 * NK;
    unsigned short* lA0 = As + wave * 32 * 32;
    unsigned short* lA1 = lA0 + 16 * 32;
    unsigned short* lB0 = Bs + wave * 32 * 32;
    unsigned short* lB1 = lB0 + 16 * 32;

    int rcol = (quad ^ ((l16 >> 1) & 3)) * 8;

    floatx4 acc[4][4];
#pragma unroll
    for (int i = 0; i < 4; ++i)
#pragma unroll
        for (int j = 0; j < 4; ++j) acc[i][j] = (floatx4)(0.0f);

    for (int kb = 0; kb < (NK / 4) / 32; ++kb) {
        int k0 = kb * 32;
        __syncthreads();
        gload_lds16(gA0 + k0, lA0);
        gload_lds16(gA1 + k0, lA1);
        gload_lds16(gB0 + k0, lB0);
        gload_lds16(gB1 + k0, lB1);
        __syncthreads();
        short8 a[4], b[4];
#pragma unroll
        for (int i = 0; i < 4; ++i)
            a[i] = *(const short8*)&As[(wm * 64 + i * 16 + l16) * 32 + rcol];
#pragma unroll
        for (int j = 0; j < 4; ++j)
            b[j] = *(const short8*)&Bs[(wn * 64 + j * 16 + l16) * 32 + rcol];
        // swapped: acc[i][j] lane(quad,l16) reg r = C[q=i*16+l16][d=j*16+quad*4+r]
#pragma unroll
        for (int i = 0; i < 4; ++i)
#pragma unroll
            for (int j = 0; j < 4; ++j)
                acc[i][j] = __builtin_amdgcn_mfma_f32_16x16x32_bf16(b[j], a[i], acc[i][j], 0, 0, 0);
    }

    float* pslice = part + (size_t)z * NQ * DIM;
#pragma unroll
    for (int i = 0; i < 4; ++i) {
        int qrow = q0 + wm * 64 + i * 16 + l16;
#pragma unroll
        for (int j = 0; j < 4; ++j) {
            int dcol = d0 + wn * 64 + j * 16 + quad * 4;
            float4 v;
            v.x = acc[i][j][0]; v.y = acc[i][j][1];
            v.z = acc[i][j][2]; v.w = acc[i][j][3];
            *(float4*)&pslice[(size_t)qrow * DIM + dcol] = v;
        }
    }
}

// ---------------------------------------------------------------------------
// reduce: out[q][d] = (sum_z part[z][q][d]) / lsum[q]
// ---------------------------------------------------------------------------
__global__ void reduce_out(const float* __restrict__ part,
                           const float* __restrict__ lsum,
                           float* __restrict__ out) {
    size_t idx = ((size_t)blockIdx.x * 256 + threadIdx.x) * 4;
    int q = (int)(idx >> 10);
    float inv = 1.0f / lsum[q];
    const size_t S = (size_t)NQ * DIM;
    float4 s0 = *(const float4*)(part + idx);
    float4 s1 = *(const float4*)(part + S + idx);
    float4 s2 = *(const float4*)(part + 2 * S + idx);
    float4 s3 = *(const float4*)(part + 3 * S + idx);
    float4 o;
    o.x = (s0.x + s1.x + s2.x + s3.x) * inv;
    o.y = (s0.y + s1.y + s2.y + s3.y) * inv;
    o.z = (s0.z + s1.z + s2.z + s3.z) * inv;
    o.w = (s0.w + s1.w + s2.w + s3.w) * inv;
    *(float4*)(out + idx) = o;
}

// ---------------------------------------------------------------------------
// GEMM 2 tier-2 (exact R10): atomics into pre-zeroed out.
// ---------------------------------------------------------------------------
__global__ void ctx_gemm(const unsigned short* __restrict__ P,
                         const unsigned short* __restrict__ Kt,
                         const float* __restrict__ lsum,
                         float* __restrict__ out) {
    __shared__ __align__(16) unsigned short As[128 * 32];
    __shared__ __align__(16) unsigned short Bs[128 * 32];
    int id = blockIdx.x;
    int r8 = id & 7;
    int t  = id >> 3;
    int x  = t & 7;
    int g  = ((t >> 3) << 3) | r8;
    int y  = g & 31;
    int z  = g >> 5;
    int q0 = y * 128;
    int d0 = x * 128;
    int kbase = z * (NK / 4);

    int tid = threadIdx.x;
    int wave = tid >> 6, lane = tid & 63;
    int wm = wave >> 1, wn = wave & 1;
    int quad = lane >> 4, l16 = lane & 15;

    int srow   = wave * 32 + (lane >> 2);
    int schunk = (((lane & 3) ^ ((lane >> 3) & 3))) * 8;
    const unsigned short* gA0 = P + (size_t)(q0 + srow) * NK + kbase + schunk;
    const unsigned short* gA1 = gA0 + (size_t)16 * NK;
    const unsigned short* gB0 = Kt + (size_t)(d0 + srow) * NK + kbase + schunk;
    const unsigned short* gB1 = gB0 + (size_t)16 * NK;
    unsigned short* lA0 = As + wave * 32 * 32;
    unsigned short* lA1 = lA0 + 16 * 32;
    unsigned short* lB0 = Bs + wave * 32 * 32;
    unsigned short* lB1 = lB0 + 16 * 32;

    int rcol = (quad ^ ((l16 >> 1) & 3)) * 8;

    floatx4 acc[4][4];
#pragma unroll
    for (int i = 0; i < 4; ++i)
#pragma unroll
        for (int j = 0; j < 4; ++j) acc[i][j] = (floatx4)(0.0f);

    for (int kb = 0; kb < (NK / 4) / 32; ++kb) {
        int k0 = kb * 32;
        __syncthreads();
        gload_lds16(gA0 + k0, lA0);
        gload_lds16(gA1 + k0, lA1);
        gload_lds16(gB0 + k0, lB0);
        gload_lds16(gB1 + k0, lB1);
        __syncthreads();
        short8 a[4], b[4];
#pragma unroll
        for (int i = 0; i < 4; ++i)
            a[i] = *(const short8*)&As[(wm * 64 + i * 16 + l16) * 32 + rcol];
#pragma unroll
        for (int j = 0; j < 4; ++j)
            b[j] = *(const short8*)&Bs[(wn * 64 + j * 16 + l16) * 32 + rcol];
#pragma unroll
        for (int i = 0; i < 4; ++i)
#pragma unroll
            for (int j = 0; j < 4; ++j)
                acc[i][j] = __builtin_amdgcn_mfma_f32_16x16x32_bf16(a[i], b[j], acc[i][j], 0, 0, 0);
    }

#pragma unroll
    for (int i = 0; i < 4; ++i) {
        float invl[4];
#pragma unroll
        for (int r = 0; r < 4; ++r)
            invl[r] = 1.0f / lsum[q0 + wm * 64 + i * 16 + quad * 4 + r];
#pragma unroll
        for (int j = 0; j < 4; ++j) {
#pragma unroll
            for (int r = 0; r < 4; ++r) {
                int qrow = q0 + wm * 64 + i * 16 + quad * 4 + r;
                int dcol = d0 + wn * 64 + j * 16 + l16;
                atomicAdd(&out[(size_t)qrow * DIM + dcol], acc[i][j][r] * invl[r]);
            }
        }
    }
}

// ---------------------------------------------------------------------------
// Path D fallback (ws too small) — correct but slow.
// ---------------------------------------------------------------------------
__global__ void fused_fallback(const float* __restrict__ Q,
                               const float* __restrict__ K,
                               float* __restrict__ out) {
    int wave = threadIdx.x >> 6, lane = threadIdx.x & 63;
    int q0 = blockIdx.x * 16 + wave * 4;
    float qv[4][16], acc[4][16], iqn[4], ls[4];
#pragma unroll
    for (int r = 0; r < 4; ++r) {
        float s = 0.f;
#pragma unroll
        for (int c = 0; c < 4; ++c) {
            float4 f = *(const float4*)(Q + (size_t)(q0 + r) * DIM + c * 256 + lane * 4);
            qv[r][c * 4 + 0] = f.x; qv[r][c * 4 + 1] = f.y;
            qv[r][c * 4 + 2] = f.z; qv[r][c * 4 + 3] = f.w;
            s += f.x * f.x + f.y * f.y + f.z * f.z + f.w * f.w;
        }
#pragma unroll
        for (int off = 32; off > 0; off >>= 1) s += __shfl_xor(s, off);
        iqn[r] = 1.0f / sqrtf(s);
        ls[r] = 0.f;
#pragma unroll
        for (int t = 0; t < 16; ++t) acc[r][t] = 0.f;
    }
    for (int k = 0; k < NK; ++k) {
        const float* kr = K + (size_t)k * DIM;
        float kv[16], ss = 0.f;
#pragma unroll
        for (int c = 0; c < 4; ++c) {
            float4 f = *(const float4*)(kr + c * 256 + lane * 4);
            kv[c * 4 + 0] = f.x; kv[c * 4 + 1] = f.y;
            kv[c * 4 + 2] = f.z; kv[c * 4 + 3] = f.w;
            ss += f.x * f.x + f.y * f.y + f.z * f.z + f.w * f.w;
        }
        float d0 = 0.f, d1 = 0.f, d2 = 0.f, d3 = 0.f;
#pragma unroll
        for (int t = 0; t < 16; ++t) {
            d0 += qv[0][t] * kv[t]; d1 += qv[1][t] * kv[t];
            d2 += qv[2][t] * kv[t]; d3 += qv[3][t] * kv[t];
        }
#pragma unroll
        for (int off = 32; off > 0; off >>= 1) {
            ss += __shfl_xor(ss, off);
            d0 += __shfl_xor(d0, off); d1 += __shfl_xor(d1, off);
            d2 += __shfl_xor(d2, off); d3 += __shfl_xor(d3, off);
        }
        float ikn = 1.0f / sqrtf(ss);
        float p0 = __expf(d0 * iqn[0] * ikn), p1 = __expf(d1 * iqn[1] * ikn);
        float p2 = __expf(d2 * iqn[2] * ikn), p3 = __expf(d3 * iqn[3] * ikn);
        ls[0] += p0; ls[1] += p1; ls[2] += p2; ls[3] += p3;
#pragma unroll
        for (int t = 0; t < 16; ++t) {
            acc[0][t] += p0 * kv[t]; acc[1][t] += p1 * kv[t];
            acc[2][t] += p2 * kv[t]; acc[3][t] += p3 * kv[t];
        }
    }
#pragma unroll
    for (int r = 0; r < 4; ++r) {
        float inv = 1.0f / ls[r];
#pragma unroll
        for (int c = 0; c < 4; ++c) {
            float4 o;
            o.x = acc[r][c * 4 + 0] * inv; o.y = acc[r][c * 4 + 1] * inv;
            o.z = acc[r][c * 4 + 2] * inv; o.w = acc[r][c * 4 + 3] * inv;
            *(float4*)(out + (size_t)(q0 + r) * DIM + c * 256 + lane * 4) = o;
        }
    }
}

// ---------------------------------------------------------------------------
// launch — tiers:
//  T1 (ws>=152M+64K): Kt[0,16M) overlap Qb/Kb, P[24,88M), part[88,152M),
//                     scalars @152M; ctx_gemm_st + reduce_out.
//  T2 (ws>=88M+64K):  exact R10 (atomics).
//  else: fallback.
// ---------------------------------------------------------------------------
extern "C" void kernel_launch(void* const* d_in, const int* in_sizes, int n_in,
                              void* d_out, int out_size, void* d_ws, size_t ws_size,
                              hipStream_t stream) {
    const float* Q = (const float*)d_in[0];
    const float* K = (const float*)d_in[1];
    float* out = (float*)d_out;
    char* ws = (char*)d_ws;

    const size_t REQ_T1 = ((size_t)152u << 20) + 65536;
    const size_t REQ_T2 = ((size_t)88u << 20) + 65536;

    if (ws_size >= REQ_T1) {
        unsigned short* Kt = (unsigned short*)(ws);
        unsigned short* Qb = (unsigned short*)(ws);
        unsigned short* Kb = (unsigned short*)(ws + (size_t)(8u << 20));
        unsigned short* P  = (unsigned short*)(ws + (size_t)(24u << 20));
        float* part   = (float*)(ws + (size_t)(88u << 20));
        float* inv_qn = (float*)(ws + (size_t)(152u << 20));
        float* inv_kn = (float*)(ws + (size_t)(152u << 20) + 16384);
        float* lsum   = (float*)(ws + (size_t)(152u << 20) + 49152);

        prep_q_zero<<<NQ / 4, 256, 0, stream>>>(Q, Qb, inv_qn, lsum, nullptr);
        prep_norm_cvt<<<NK / 4, 256, 0, stream>>>(K, Kb, inv_kn);
        score_gemm<<<2048, 256, 0, stream>>>(Qb, Kb, inv_qn, inv_kn, P, lsum);
        transpose_cvt<<<dim3(NK / 64, DIM / 64), 256, 0, stream>>>(K, Kt);
        ctx_gemm_st<<<1024, 256, 0, stream>>>(P, Kt, part);
        reduce_out<<<NQ * DIM / 1024, 256, 0, stream>>>(part, lsum, out);
    } else if (ws_size >= REQ_T2) {
        unsigned short* Kt = (unsigned short*)(ws);
        unsigned short* Qb = (unsigned short*)(ws);
        unsigned short* Kb = (unsigned short*)(ws + (size_t)(8u << 20));
        unsigned short* P  = (unsigned short*)(ws + (size_t)(24u << 20));
        float* inv_qn = (float*)(ws + (size_t)(88u << 20));
        float* inv_kn = (float*)(ws + (size_t)(88u << 20) + 16384);
        float* lsum   = (float*)(ws + (size_t)(88u << 20) + 49152);

        prep_q_zero<<<NQ / 4, 256, 0, stream>>>(Q, Qb, inv_qn, lsum, out);
        prep_norm_cvt<<<NK / 4, 256, 0, stream>>>(K, Kb, inv_kn);
        score_gemm<<<2048, 256, 0, stream>>>(Qb, Kb, inv_qn, inv_kn, P, lsum);
        transpose_cvt<<<dim3(NK / 64, DIM / 64), 256, 0, stream>>>(K, Kt);
        ctx_gemm<<<1024, 256, 0, stream>>>(P, Kt, lsum, out);
    } else {
        fused_fallback<<<NQ / 16, 256, 0, stream>>>(Q, K, out);
    }
}